// Round 1
// baseline (1599.712 us; speedup 1.0000x reference)
//
#include <hip/hip_runtime.h>
#include <hip/hip_bf16.h>
#include <stdint.h>

// GraphSAGE layer, N=16384, F_IN=F_OUT=256.
// out = (adj@ (x@W1))/deg + x@W2 + bias
//   K0: WT[n][k] (bf16)  = transpose of [W1|W2]
//   K1: yT[n][m] (bf16)  = (x@W1)^T ;  z[m][n] (f32) = x@W2 + bias
//   K2: out[m][n] = (adj @ y)[m][n]/deg[m] + z[m][n]   (adj read once, deg fused)

typedef short bf16x8 __attribute__((ext_vector_type(8)));
typedef float f32x4  __attribute__((ext_vector_type(4)));

__device__ __forceinline__ uint32_t pack_bf16_rne(float lo, float hi) {
    uint32_t ul = __float_as_uint(lo);
    uint32_t uh = __float_as_uint(hi);
    ul = (ul + 0x7fffu + ((ul >> 16) & 1u)) >> 16;
    uh = (uh + 0x7fffu + ((uh >> 16) & 1u)) >> 16;
    return ul | (uh << 16);
}

// ---------------- K0: transpose weight [512,256] f32 -> WT [512(n)][256(k)] bf16
// WT[n][k] = n<256 ? weight[k][n] : weight[256+k][n-256]
__global__ __launch_bounds__(256) void k_transpose_w(const float* __restrict__ w,
                                                     uint16_t* __restrict__ wt) {
    int idx = blockIdx.x * 256 + threadIdx.x;   // 0..131071
    int n = idx >> 8;
    int k = idx & 255;
    int row = (n < 256) ? k : (256 + k);
    int col = (n < 256) ? n : (n - 256);
    uint32_t u = __float_as_uint(w[row * 256 + col]);
    u = (u + 0x7fffu + ((u >> 16) & 1u)) >> 16;
    wt[idx] = (uint16_t)u;
}

// ---------------- K1: small GEMM  [16384,256] @ [256,512] -> yT (cols 0..255) / z (cols 256..511)
// grid (4 col-tiles, 128 row-tiles), 256 threads, tile 128x128, BK=32, 8 K-iters
__global__ __launch_bounds__(256) void k_small_gemm(const float* __restrict__ x,
                                                    const uint16_t* __restrict__ wt,
                                                    const float* __restrict__ bias,
                                                    uint16_t* __restrict__ yT,
                                                    float* __restrict__ z) {
    __shared__ uint16_t As[128 * 32];  // [m][k] bf16
    __shared__ uint16_t Bs[128 * 32];  // [n][k] bf16

    const int t  = threadIdx.x;
    const int ct = blockIdx.x;        // 0..3  (combined col tile)
    const int rt = blockIdx.y;        // 0..127
    const int m0 = rt * 128;
    const int n0 = ct * 128;

    const int lane = t & 63, w = t >> 6;
    const int wr = w >> 1, wc = w & 1;          // wave computes 64x64
    const int l15 = lane & 15, quad = lane >> 4;

    f32x4 acc[4][4] = {};

    float4 a_reg[4];
    uint4  b_reg[2];

    // prefetch k0 = 0
#pragma unroll
    for (int i = 0; i < 4; ++i) {
        int f4 = t + 256 * i, row = f4 >> 3, c4 = f4 & 7;
        a_reg[i] = *(const float4*)(x + (m0 + row) * 256 + c4 * 4);
    }
#pragma unroll
    for (int i = 0; i < 2; ++i) {
        int u4 = t + 256 * i, n_l = u4 >> 2, part = u4 & 3;
        b_reg[i] = *(const uint4*)(wt + (n0 + n_l) * 256 + part * 8);
    }

    for (int kk = 0; kk < 8; ++kk) {
        __syncthreads();
#pragma unroll
        for (int i = 0; i < 4; ++i) {
            int f4 = t + 256 * i, row = f4 >> 3, c4 = f4 & 7;
            uint2 p;
            p.x = pack_bf16_rne(a_reg[i].x, a_reg[i].y);
            p.y = pack_bf16_rne(a_reg[i].z, a_reg[i].w);
            *(uint2*)(As + row * 32 + c4 * 4) = p;
        }
#pragma unroll
        for (int i = 0; i < 2; ++i) {
            int u4 = t + 256 * i, n_l = u4 >> 2, part = u4 & 3;
            *(uint4*)(Bs + n_l * 32 + part * 8) = b_reg[i];
        }
        if (kk < 7) {
            int k0 = (kk + 1) * 32;
#pragma unroll
            for (int i = 0; i < 4; ++i) {
                int f4 = t + 256 * i, row = f4 >> 3, c4 = f4 & 7;
                a_reg[i] = *(const float4*)(x + (m0 + row) * 256 + k0 + c4 * 4);
            }
#pragma unroll
            for (int i = 0; i < 2; ++i) {
                int u4 = t + 256 * i, n_l = u4 >> 2, part = u4 & 3;
                b_reg[i] = *(const uint4*)(wt + (n0 + n_l) * 256 + k0 + part * 8);
            }
        }
        __syncthreads();

        bf16x8 a_frag[4], b_frag[4];
#pragma unroll
        for (int fr = 0; fr < 4; ++fr)
            a_frag[fr] = *(const bf16x8*)(As + (wr * 64 + fr * 16 + l15) * 32 + quad * 8);
#pragma unroll
        for (int fc = 0; fc < 4; ++fc)
            b_frag[fc] = *(const bf16x8*)(Bs + (wc * 64 + fc * 16 + l15) * 32 + quad * 8);
#pragma unroll
        for (int fr = 0; fr < 4; ++fr)
#pragma unroll
            for (int fc = 0; fc < 4; ++fc)
                acc[fr][fc] = __builtin_amdgcn_mfma_f32_16x16x32_bf16(
                    a_frag[fr], b_frag[fc], acc[fr][fc], 0, 0, 0);
    }

    // epilogue: C/D layout col=lane&15, row=quad*4+reg
    if (ct < 2) {
        // y^T (bf16): yT[n][m], lane's 4 regs are 4 consecutive m -> one 8B store
#pragma unroll
        for (int fr = 0; fr < 4; ++fr) {
            int m_base = m0 + wr * 64 + fr * 16 + quad * 4;
#pragma unroll
            for (int fc = 0; fc < 4; ++fc) {
                int n_g = n0 + wc * 64 + fc * 16 + l15;   // 0..255
                uint2 pp;
                pp.x = pack_bf16_rne(acc[fr][fc][0], acc[fr][fc][1]);
                pp.y = pack_bf16_rne(acc[fr][fc][2], acc[fr][fc][3]);
                *(uint2*)(yT + (size_t)n_g * 16384 + m_base) = pp;
            }
        }
    } else {
        // z (f32, row-major) + bias
#pragma unroll
        for (int fr = 0; fr < 4; ++fr) {
            int m_base = m0 + wr * 64 + fr * 16 + quad * 4;
#pragma unroll
            for (int fc = 0; fc < 4; ++fc) {
                int n_g = (n0 - 256) + wc * 64 + fc * 16 + l15;  // 0..255
                float bv = bias[n_g];
#pragma unroll
                for (int r = 0; r < 4; ++r)
                    z[(size_t)(m_base + r) * 256 + n_g] = acc[fr][fc][r] + bv;
            }
        }
    }
}

// ---------------- K2: big GEMM  out[16384,256] = (adj @ y)/deg + z
// grid 256 (64-row tiles, all 256 cols), 512 threads (8 waves, each 32x64), BK=32, 512 K-iters
__global__ __launch_bounds__(512) void k_big_gemm(const int* __restrict__ adj,
                                                  const uint16_t* __restrict__ yT,
                                                  const float* __restrict__ z,
                                                  float* __restrict__ out) {
    __shared__ uint16_t As[64 * 32];     // [m][k] bf16, 4 KB
    __shared__ uint16_t Bs[256 * 32];    // [n][k] bf16, 16 KB
    __shared__ int degs[64];

    const int t = threadIdx.x;
    const int m0 = blockIdx.x * 64;
    const int lane = t & 63, w = t >> 6;           // w 0..7
    const int wr = w >> 2, wc = w & 3;             // wave: rows wr*32+ (2 frags), cols wc*64+ (4 frags)
    const int l15 = lane & 15, quad = lane >> 4;

    f32x4 acc[2][4] = {};

    // A staging: 64 rows x 32 ints = 512 int4, one per thread
    const int a_row = t >> 3, a_c4 = t & 7;
    const int4* pa = (const int4*)(adj + (size_t)(m0 + a_row) * 16384) + a_c4;
    uint16_t* As_w = As + a_row * 32 + a_c4 * 4;

    // B staging: 256 rows x 32 bf16 = 1024 uint4, two per thread
    const int b_n = t >> 2, b_part = t & 3;        // rows b_n and b_n+128
    const uint4* pb0 = (const uint4*)yT + (size_t)b_n * 2048 + b_part;
    const uint4* pb1 = pb0 + (size_t)128 * 2048;
    uint16_t* Bs_w0 = Bs + b_n * 32 + b_part * 8;
    uint16_t* Bs_w1 = Bs_w0 + 128 * 32;

    int4 a_reg = *pa; pa += 8;
    uint4 b_reg0 = *pb0; pb0 += 4;
    uint4 b_reg1 = *pb1; pb1 += 4;
    int degp = 0;

    for (int kk = 0; kk < 512; ++kk) {
        __syncthreads();
        // stage kk (int -> bf16 pack: (a|b<<16)*0x3F80 gives packed {0,1.0} bf16 pair)
        degp += a_reg.x + a_reg.y + a_reg.z + a_reg.w;
        uint2 p;
        p.x = (uint32_t)(a_reg.x | (a_reg.y << 16)) * 0x3F80u;
        p.y = (uint32_t)(a_reg.z | (a_reg.w << 16)) * 0x3F80u;
        *(uint2*)As_w = p;
        *(uint4*)Bs_w0 = b_reg0;
        *(uint4*)Bs_w1 = b_reg1;
        if (kk < 511) {           // prefetch kk+1 (hidden behind MFMA below)
            a_reg = *pa; pa += 8;
            b_reg0 = *pb0; pb0 += 4;
            b_reg1 = *pb1; pb1 += 4;
        }
        __syncthreads();

        bf16x8 a_frag[2], b_frag[4];
#pragma unroll
        for (int fr = 0; fr < 2; ++fr)
            a_frag[fr] = *(const bf16x8*)(As + (wr * 32 + fr * 16 + l15) * 32 + quad * 8);
#pragma unroll
        for (int fc = 0; fc < 4; ++fc)
            b_frag[fc] = *(const bf16x8*)(Bs + (wc * 64 + fc * 16 + l15) * 32 + quad * 8);
#pragma unroll
        for (int fr = 0; fr < 2; ++fr)
#pragma unroll
            for (int fc = 0; fc < 4; ++fc)
                acc[fr][fc] = __builtin_amdgcn_mfma_f32_16x16x32_bf16(
                    a_frag[fr], b_frag[fc], acc[fr][fc], 0, 0, 0);
    }

    // deg: each row owned by 8 consecutive lanes of one wave
    degp += __shfl_down(degp, 4);
    degp += __shfl_down(degp, 2);
    degp += __shfl_down(degp, 1);
    if ((t & 7) == 0) degs[t >> 3] = degp;
    __syncthreads();

    // epilogue: out = acc/deg + z
#pragma unroll
    for (int fr = 0; fr < 2; ++fr) {
#pragma unroll
        for (int r = 0; r < 4; ++r) {
            int m_l = wr * 32 + fr * 16 + quad * 4 + r;
            float inv = 1.0f / (float)degs[m_l];
            size_t mrow = (size_t)(m0 + m_l) * 256;
#pragma unroll
            for (int fc = 0; fc < 4; ++fc) {
                int n_g = wc * 64 + fc * 16 + l15;
                out[mrow + n_g] = acc[fr][fc][r] * inv + z[mrow + n_g];
            }
        }
    }
}

extern "C" void kernel_launch(void* const* d_in, const int* in_sizes, int n_in,
                              void* d_out, int out_size, void* d_ws, size_t ws_size,
                              hipStream_t stream) {
    const float* x      = (const float*)d_in[0];
    const int*   adj    = (const int*)d_in[1];
    const float* weight = (const float*)d_in[2];
    const float* bias   = (const float*)d_in[3];
    float* out = (float*)d_out;

    // workspace layout: WT (256 KB) | yT (8 MB bf16) | z (16 MB f32)  ~= 24.3 MiB
    uint16_t* wt = (uint16_t*)d_ws;
    uint16_t* yT = (uint16_t*)((char*)d_ws + 262144);
    float*    z  = (float*)((char*)d_ws + 262144 + 8388608);

    k_transpose_w<<<512, 256, 0, stream>>>(weight, wt);
    k_small_gemm<<<dim3(4, 128), 256, 0, stream>>>(x, wt, bias, yT, z);
    k_big_gemm<<<256, 512, 0, stream>>>(adj, yT, z, out);
}